// Round 6
// baseline (122.235 us; speedup 1.0000x reference)
//
#include <hip/hip_runtime.h>
#include <math.h>

#define FRAME_LEN 512
#define HOP       256
#define NFREQ     257
#define NFREQ_PAD 288
#define NBATCH    64
#define NSAMP     160000
#define TFRAMES   624
#define EPS       1.1920928955078125e-07f
#define XBLKS     5000

typedef __attribute__((ext_vector_type(8))) short short8;
typedef __attribute__((ext_vector_type(4))) float f32x4;

static __device__ __forceinline__ unsigned int f2bf(float f) {
    unsigned int u = __float_as_uint(f);
    return (u + 0x7fffu + ((u >> 16) & 1u)) >> 16;          // RNE to bf16
}
static __device__ __forceinline__ float bf2f_lo(unsigned int p) {
    return __uint_as_float(p << 16);
}
static __device__ __forceinline__ float bf2f_hi(unsigned int p) {
    return __uint_as_float(p & 0xffff0000u);
}
static __device__ __forceinline__ uint4 pack8(float4 a, float4 b) {
    uint4 r;
    r.x = f2bf(a.x) | (f2bf(a.y) << 16);
    r.y = f2bf(a.z) | (f2bf(a.w) << 16);
    r.z = f2bf(b.x) | (f2bf(b.y) << 16);
    r.w = f2bf(b.z) | (f2bf(b.w) << 16);
    return r;
}
static __device__ __forceinline__ void gload_lds16(const void* g, void* l) {
    __builtin_amdgcn_global_load_lds(
        (const __attribute__((address_space(1))) void*)g,
        (__attribute__((address_space(3))) void*)l, 16, 0, 0);
}

// ------------------------------------------------- prep: tables + x->bf16 ---
__global__ __launch_bounds__(256) void prep(const float* __restrict__ x,
                                            unsigned short* __restrict__ xbf,
                                            unsigned short* __restrict__ Wc,
                                            unsigned short* __restrict__ Ws) {
    if (blockIdx.x < XBLKS) {                   // x -> bf16, 8 elems/thread
        int i = blockIdx.x * 256 + threadIdx.x;
        const float4* src = (const float4*)x + (size_t)i * 2;
        float4 a = src[0], b = src[1];
        *(uint4*)(xbf + (size_t)i * 8) = pack8(a, b);
    } else {                                    // DFT tables, bf16, 288 rows
        int f = blockIdx.x - XBLKS;             // 0..287
        for (int n = threadIdx.x; n < FRAME_LEN; n += 256) {
            unsigned short c = 0, s = 0;
            if (f < NFREQ) {
                float w = 0.5f * (1.0f - cosf(2.0f * (float)M_PI * (float)n / (float)FRAME_LEN));
                int r = (f * n) & (FRAME_LEN - 1);
                float ang = (float)r * (2.0f * (float)M_PI / (float)FRAME_LEN);
                float sv, cv;
                sincosf(ang, &sv, &cv);
                c = (unsigned short)f2bf(cv * w);
                s = (unsigned short)f2bf(sv * w);   // i = +sin*w
            }
            Wc[f * FRAME_LEN + n] = c;
            Ws[f * FRAME_LEN + n] = s;
        }
    }
}

// ---------------- staging: A (4 gloads) + B (1 gload), k-major chunked ------
// As[buf][kchunk(4)][row 256][8k]  Bs[buf][tbl(2)][kchunk(4)][f 32][8k]
static __device__ __forceinline__ void stage(
    unsigned short* AsB, unsigned short* BsB, int buf, int p, int c,
    const unsigned short* xb, const unsigned short* Wc, const unsigned short* Ws,
    int ftile, int tid)
{
    const int k0 = c * 32;
    int t = p * 256 + tid;
    if (t > TFRAMES - 1) t = TFRAMES - 1;       // clamped rows are predicated out
    const unsigned short* srcA = xb + t * HOP + k0;
    #pragma unroll
    for (int j = 0; j < 4; j++)
        gload_lds16(srcA + j * 8, AsB + buf * 8192 + j * 2048 + tid * 8);
    const unsigned short* tb = (tid < 128) ? Wc : Ws;
    const int bf = ftile * 32 + (tid & 31);     // < 288 (padded tables)
    const int ch = (tid & 127) >> 5;
    gload_lds16(tb + bf * 512 + k0 + ch * 8, BsB + buf * 2048 + tid * 8);
}

// ---------------- one pass: MF m-frags per wave, 16 K-chunks of 32 ----------
template<int P, int MF, int WS>
static __device__ __forceinline__ void do_pass(
    int& buf, unsigned short* AsB, unsigned short* BsB,
    const unsigned short* xb, const unsigned short* Wc, const unsigned short* Ws,
    int ftile, int tid, int wid, int lrow, int lhi, int b,
    float* __restrict__ mag, float* ssum, float* ssq,
    unsigned int stash[10][2][2])
{
    f32x4 ar[MF][2] = {};
    f32x4 ai[MF][2] = {};
    #pragma unroll
    for (int c = 0; c < 16; c++) {
        const int nit = P * 16 + c + 1;
        if (nit < 48)
            stage(AsB, BsB, buf ^ 1, nit >> 4, nit & 15, xb, Wc, Ws, ftile, tid);
        short8 av[MF], bcv[2], bsv[2];
        #pragma unroll
        for (int mf = 0; mf < MF; mf++)
            av[mf] = *(const short8*)(AsB + buf * 8192 + lhi * 2048 +
                                      (wid * WS + mf * 16 + lrow) * 8);
        #pragma unroll
        for (int nf = 0; nf < 2; nf++) {
            bcv[nf] = *(const short8*)(BsB + buf * 2048 + lhi * 256 + (nf * 16 + lrow) * 8);
            bsv[nf] = *(const short8*)(BsB + buf * 2048 + 1024 + lhi * 256 + (nf * 16 + lrow) * 8);
        }
        #pragma unroll
        for (int mf = 0; mf < MF; mf++) {
            #pragma unroll
            for (int nf = 0; nf < 2; nf++) {
                ar[mf][nf] = __builtin_amdgcn_mfma_f32_16x16x32_bf16(
                    av[mf], bcv[nf], ar[mf][nf], 0, 0, 0);
                ai[mf][nf] = __builtin_amdgcn_mfma_f32_16x16x32_bf16(
                    av[mf], bsv[nf], ai[mf][nf], 0, 0, 0);
            }
        }
        __syncthreads();
        buf ^= 1;
    }
    // epilogue: mag write + stats + packed stash
    #pragma unroll
    for (int mf = 0; mf < MF; mf++) {
        const int tile = (P < 2) ? (P * 16 + wid * 4 + mf) : (32 + wid * 2 + mf);
        const int t = tile * 16 + lhi * 4;
        const bool tv = (tile < 39);            // tile 39 = padded t >= 624
        #pragma unroll
        for (int nf = 0; nf < 2; nf++) {
            const int f = ftile * 32 + nf * 16 + lrow;
            const float m0 = sqrtf(ar[mf][nf][0] * ar[mf][nf][0] + ai[mf][nf][0] * ai[mf][nf][0]);
            const float m1 = sqrtf(ar[mf][nf][1] * ar[mf][nf][1] + ai[mf][nf][1] * ai[mf][nf][1]);
            const float m2 = sqrtf(ar[mf][nf][2] * ar[mf][nf][2] + ai[mf][nf][2] * ai[mf][nf][2]);
            const float m3 = sqrtf(ar[mf][nf][3] * ar[mf][nf][3] + ai[mf][nf][3] * ai[mf][nf][3]);
            if (tv && f < NFREQ) {
                float4 o = make_float4(m0, m1, m2, m3);
                *(float4*)(mag + ((size_t)b * NFREQ + f) * TFRAMES + t) = o;
            }
            const float c0 = fmaxf(m0, EPS), c1 = fmaxf(m1, EPS);
            const float c2 = fmaxf(m2, EPS), c3 = fmaxf(m3, EPS);
            if (tv) {
                ssum[nf] += (c0 + c1) + (c2 + c3);
                ssq[nf]  += (c0 * c0 + c1 * c1) + (c2 * c2 + c3 * c3);
            }
            const int si = (P < 2) ? (P * 4 + mf) : (8 + mf);
            stash[si][nf][0] = f2bf(c0) | (f2bf(c1) << 16);
            stash[si][nf][1] = f2bf(c2) | (f2bf(c3) << 16);
        }
    }
}

// ---------------- fused stft + magnitude + row-normalize --------------------
__global__ __launch_bounds__(256) void stft_fused(
    const unsigned short* __restrict__ xbf, const unsigned short* __restrict__ Wc,
    const unsigned short* __restrict__ Ws, float* __restrict__ mag,
    float* __restrict__ feat)
{
    __shared__ unsigned short As[2][4][256][8];     // 32 KB
    __shared__ unsigned short Bs[2][2][4][32][8];   // 8 KB
    const int tid = threadIdx.x;
    // bijective XCD swizzle: 576 = 8*72; 9 blocks of one batch -> same XCD L2
    const int logical = ((int)blockIdx.x & 7) * 72 + ((int)blockIdx.x >> 3);
    const int b = logical / 9;
    const int ftile = logical - b * 9;
    const int wid = tid >> 6, lane = tid & 63, lrow = lane & 15, lhi = lane >> 4;
    const unsigned short* xb = xbf + (size_t)b * NSAMP;
    unsigned short* AsB = &As[0][0][0][0];
    unsigned short* BsB = &Bs[0][0][0][0][0];

    float ssum[2] = {0.f, 0.f}, ssq[2] = {0.f, 0.f};
    unsigned int stash[10][2][2];

    stage(AsB, BsB, 0, 0, 0, xb, Wc, Ws, ftile, tid);
    __syncthreads();
    int buf = 0;
    do_pass<0, 4, 64>(buf, AsB, BsB, xb, Wc, Ws, ftile, tid, wid, lrow, lhi, b, mag, ssum, ssq, stash);
    do_pass<1, 4, 64>(buf, AsB, BsB, xb, Wc, Ws, ftile, tid, wid, lrow, lhi, b, mag, ssum, ssq, stash);
    do_pass<2, 2, 32>(buf, AsB, BsB, xb, Wc, Ws, ftile, tid, wid, lrow, lhi, b, mag, ssum, ssq, stash);

    // reduce over lhi groups (lanes lrow, lrow+16, +32, +48)
    #pragma unroll
    for (int nf = 0; nf < 2; nf++) {
        ssum[nf] += __shfl_xor(ssum[nf], 16, 64);
        ssum[nf] += __shfl_xor(ssum[nf], 32, 64);
        ssq[nf]  += __shfl_xor(ssq[nf], 16, 64);
        ssq[nf]  += __shfl_xor(ssq[nf], 32, 64);
    }
    float* red = (float*)AsB;                   // alias: [wid][nf][lrow][2]
    if (lane < 16) {
        #pragma unroll
        for (int nf = 0; nf < 2; nf++) {
            red[((wid * 2 + nf) * 16 + lane) * 2 + 0] = ssum[nf];
            red[((wid * 2 + nf) * 16 + lane) * 2 + 1] = ssq[nf];
        }
    }
    __syncthreads();
    float mean[2], inv[2];
    #pragma unroll
    for (int nf = 0; nf < 2; nf++) {
        float S = 0.f, Q = 0.f;
        #pragma unroll
        for (int w = 0; w < 4; w++) {
            S += red[((w * 2 + nf) * 16 + lrow) * 2 + 0];
            Q += red[((w * 2 + nf) * 16 + lrow) * 2 + 1];
        }
        const float mu = S * (1.0f / (float)TFRAMES);
        float var = (Q - (float)TFRAMES * mu * mu) * (1.0f / (float)(TFRAMES - 1));
        var = fmaxf(var, 0.f);
        mean[nf] = mu;
        inv[nf] = 1.0f / (sqrtf(var) + EPS);
    }
    // feat from stash
    #pragma unroll
    for (int si = 0; si < 10; si++) {
        const int tile = (si < 8) ? ((si >> 2) * 16 + wid * 4 + (si & 3))
                                  : (32 + wid * 2 + (si - 8));
        const int t = tile * 16 + lhi * 4;
        if (tile < 39) {
            #pragma unroll
            for (int nf = 0; nf < 2; nf++) {
                const int f = ftile * 32 + nf * 16 + lrow;
                if (f < NFREQ) {
                    const float c0 = bf2f_lo(stash[si][nf][0]);
                    const float c1 = bf2f_hi(stash[si][nf][0]);
                    const float c2 = bf2f_lo(stash[si][nf][1]);
                    const float c3 = bf2f_hi(stash[si][nf][1]);
                    float4 o = make_float4((c0 - mean[nf]) * inv[nf],
                                           (c1 - mean[nf]) * inv[nf],
                                           (c2 - mean[nf]) * inv[nf],
                                           (c3 - mean[nf]) * inv[nf]);
                    *(float4*)(feat + ((size_t)b * NFREQ + f) * TFRAMES + t) = o;
                }
            }
        }
    }
}

// ---------------------------------------------------------------- launch ----
extern "C" void kernel_launch(void* const* d_in, const int* in_sizes, int n_in,
                              void* d_out, int out_size, void* d_ws, size_t ws_size,
                              hipStream_t stream) {
    const float* x = (const float*)d_in[0];
    unsigned short* Wc  = (unsigned short*)d_ws;            // 288*512 bf16
    unsigned short* Ws  = Wc + NFREQ_PAD * FRAME_LEN;       // 288*512 bf16
    unsigned short* xbf = Ws + NFREQ_PAD * FRAME_LEN;       // 64*160000 bf16
    float* mag  = (float*)d_out;                            // [64][257][624]
    float* feat = mag + (size_t)NBATCH * NFREQ * TFRAMES;

    prep<<<XBLKS + NFREQ_PAD, 256, 0, stream>>>(x, xbf, Wc, Ws);

    // 64 batches x 9 f-tiles; full 624-frame rows per block (fused normalize)
    stft_fused<<<NBATCH * 9, 256, 0, stream>>>(xbf, Wc, Ws, mag, feat);
}

// Round 7
// 63.931 us; speedup vs baseline: 1.9120x; 1.9120x over previous
//
#include <hip/hip_runtime.h>
#include <math.h>

#define FRAME_LEN 512
#define HOP       256
#define NFREQ     257
#define NFREQ_PAD 288
#define NBATCH    64
#define NSAMP     160000
#define TFRAMES   624
#define EPS       1.1920928955078125e-07f

#define MT 256                 // frames per tile; 156 M-tiles exactly
#define FT 32                  // freq bins per tile
#define BK 64                  // K chunk per stage
#define NK (FRAME_LEN / BK)    // 8 K-iterations
#define XBLKS 5000

typedef __attribute__((ext_vector_type(8))) short short8;   // 8 bf16
typedef __attribute__((ext_vector_type(4))) float f32x4;    // MFMA acc

static __device__ __forceinline__ unsigned int f2bf(float f) {
    unsigned int u = __float_as_uint(f);
    return (u + 0x7fffu + ((u >> 16) & 1u)) >> 16;          // RNE to bf16
}
static __device__ __forceinline__ uint4 pack8(float4 a, float4 b) {
    uint4 r;
    r.x = f2bf(a.x) | (f2bf(a.y) << 16);
    r.y = f2bf(a.z) | (f2bf(a.w) << 16);
    r.z = f2bf(b.x) | (f2bf(b.y) << 16);
    r.w = f2bf(b.z) | (f2bf(b.w) << 16);
    return r;
}
static __device__ __forceinline__ void gload_lds16(const void* g, void* l) {
    __builtin_amdgcn_global_load_lds(
        (const __attribute__((address_space(1))) void*)g,
        (__attribute__((address_space(3))) void*)l, 16, 0, 0);
}

// ------------------------------------------------- prep: tables + x->bf16 ---
__global__ __launch_bounds__(256) void prep(const float* __restrict__ x,
                                            unsigned short* __restrict__ xbf,
                                            unsigned short* __restrict__ Wc,
                                            unsigned short* __restrict__ Ws) {
    if (blockIdx.x < XBLKS) {                   // x -> bf16, 8 elems/thread
        int i = blockIdx.x * 256 + threadIdx.x;
        const float4* src = (const float4*)x + (size_t)i * 2;
        float4 a = src[0], b = src[1];
        *(uint4*)(xbf + (size_t)i * 8) = pack8(a, b);
    } else {                                    // DFT tables, bf16, 288 rows
        int f = blockIdx.x - XBLKS;             // 0..287
        for (int n = threadIdx.x; n < FRAME_LEN; n += 256) {
            unsigned short c = 0, s = 0;
            if (f < NFREQ) {
                float w = 0.5f * (1.0f - cosf(2.0f * (float)M_PI * (float)n / (float)FRAME_LEN));
                int r = (f * n) & (FRAME_LEN - 1);
                float ang = (float)r * (2.0f * (float)M_PI / (float)FRAME_LEN);
                float sv, cv;
                sincosf(ang, &sv, &cv);
                c = (unsigned short)f2bf(cv * w);
                s = (unsigned short)f2bf(sv * w);   // i = +sin*w
            }
            Wc[f * FRAME_LEN + n] = c;
            Ws[f * FRAME_LEN + n] = s;
        }
    }
}

// ---------------- stft via bf16 MFMA, MT=256 / mf=4, 2-phase LDS dbuf -------
__global__ __launch_bounds__(256) void stft_mfma(
    const unsigned short* __restrict__ xbf, const unsigned short* __restrict__ Wc,
    const unsigned short* __restrict__ Ws, float* __restrict__ mag)
{
    __shared__ unsigned short As[2][MT][BK];    // 2 x 32 KB, linear dest
    __shared__ unsigned short Bs[2][2][FT][BK]; // 2 x 8 KB (cos, sin)

    const int tid = threadIdx.x;
    // Bijective XCD swizzle (m204 general form): nwg=1404, q=175, r=4.
    // 9 consecutive logical ids (same A-tile) land on one XCD L2.
    const int xcd = blockIdx.x & 7;
    const int slot = blockIdx.x >> 3;
    const int logical = (xcd < 4 ? xcd * 176 : 704 + (xcd - 4) * 175) + slot;
    const int tileM = logical / 9;              // 0..155
    const int tileF = logical % 9;              // 0..8
    const int wid = tid >> 6;
    const int lane = tid & 63;
    const int lrow = lane & 15;
    const int lhi = lane >> 4;

    // k0-invariant per-lane staging sources (XOR swizzle on SOURCE chunk)
    const unsigned short* pA[8];
    #pragma unroll
    for (int j = 0; j < 8; j++) {
        int idx = wid * 8 + j;                  // 0..31, 8 rows each
        int row = idx * 8 + (lane >> 3);        // 0..255
        int m = tileM * MT + row;               // < 39936 exact
        int b = m / TFRAMES;
        int t = m - b * TFRAMES;
        int chunk = (lane & 7) ^ (row & 7);
        pA[j] = xbf + (size_t)b * NSAMP + t * HOP + chunk * 8;
    }
    const unsigned short* pB[2];
    #pragma unroll
    for (int j = 0; j < 2; j++) {
        int i = wid * 2 + j;                    // 0..7: 0-3 cos, 4-7 sin
        int row = (i & 3) * 8 + (lane >> 3);
        int f = tileF * FT + row;               // < 288 (padded tables)
        int chunk = (lane & 7) ^ (row & 7);
        const unsigned short* tbl = (i & 4) ? Ws : Wc;
        pB[j] = tbl + f * FRAME_LEN + chunk * 8;
    }

    f32x4 accr[4][2] = {};
    f32x4 acci[4][2] = {};

    // ---- prologue: stage k0=0 into buf 0
    #pragma unroll
    for (int j = 0; j < 8; j++)
        gload_lds16(pA[j], (unsigned short*)As[0] + (wid * 8 + j) * 512);
    #pragma unroll
    for (int j = 0; j < 2; j++)
        gload_lds16(pB[j], (unsigned short*)Bs[0] + (wid * 2 + j) * 512);
    __syncthreads();

    for (int it = 0; it < NK; it++) {
        const int cur = it & 1;
        // ---- issue next-tile loads into other buffer (overlap with compute)
        if (it < NK - 1) {
            const int k0 = (it + 1) * BK;
            #pragma unroll
            for (int j = 0; j < 8; j++)
                gload_lds16(pA[j] + k0, (unsigned short*)As[cur ^ 1] + (wid * 8 + j) * 512);
            #pragma unroll
            for (int j = 0; j < 2; j++)
                gload_lds16(pB[j] + k0, (unsigned short*)Bs[cur ^ 1] + (wid * 2 + j) * 512);
        }
        // ---- compute current buffer: wave owns rows wid*64 .. wid*64+63
        #pragma unroll
        for (int ks = 0; ks < 2; ks++) {
            short8 a[4], bc[2], bsn[2];
            const int c = (ks * 4 + lhi) ^ (lrow & 7);
            #pragma unroll
            for (int mf = 0; mf < 4; mf++)
                a[mf] = *(const short8*)&As[cur][wid * 64 + mf * 16 + lrow][c * 8];
            #pragma unroll
            for (int nf = 0; nf < 2; nf++) {
                bc[nf]  = *(const short8*)&Bs[cur][0][nf * 16 + lrow][c * 8];
                bsn[nf] = *(const short8*)&Bs[cur][1][nf * 16 + lrow][c * 8];
            }
            #pragma unroll
            for (int mf = 0; mf < 4; mf++) {
                #pragma unroll
                for (int nf = 0; nf < 2; nf++) {
                    accr[mf][nf] = __builtin_amdgcn_mfma_f32_16x16x32_bf16(
                        a[mf], bc[nf], accr[mf][nf], 0, 0, 0);
                    acci[mf][nf] = __builtin_amdgcn_mfma_f32_16x16x32_bf16(
                        a[mf], bsn[nf], acci[mf][nf], 0, 0, 0);
                }
            }
        }
        __syncthreads();   // next buffer's loads landed; prior reads done
    }

    // ---- epilogue: mag = sqrt(r^2 + i^2), float4 over 4 consecutive t
    #pragma unroll
    for (int mf = 0; mf < 4; mf++) {
        int m0 = tileM * MT + wid * 64 + mf * 16 + lhi * 4;
        int b = m0 / TFRAMES;
        int t = m0 - b * TFRAMES;               // %4==0, run stays in batch
        #pragma unroll
        for (int nf = 0; nf < 2; nf++) {
            int f = tileF * FT + nf * 16 + lrow;
            if (f < NFREQ) {
                float4 o;
                o.x = sqrtf(accr[mf][nf][0] * accr[mf][nf][0] + acci[mf][nf][0] * acci[mf][nf][0]);
                o.y = sqrtf(accr[mf][nf][1] * accr[mf][nf][1] + acci[mf][nf][1] * acci[mf][nf][1]);
                o.z = sqrtf(accr[mf][nf][2] * accr[mf][nf][2] + acci[mf][nf][2] * acci[mf][nf][2]);
                o.w = sqrtf(accr[mf][nf][3] * accr[mf][nf][3] + acci[mf][nf][3] * acci[mf][nf][3]);
                *(float4*)(mag + ((size_t)b * NFREQ + f) * TFRAMES + t) = o;
            }
        }
    }
}

// ------------------------------------------- normalize: warp-per-row, f4 ----
__global__ __launch_bounds__(256) void normalize(const float* __restrict__ mag,
                                                 float* __restrict__ feat)
{
    const int row = blockIdx.x * 4 + (threadIdx.x >> 6);    // b*NFREQ+f
    const int lane = threadIdx.x & 63;
    const float* mp = mag + (size_t)row * TFRAMES;

    float4 v[3];
    float sum = 0.f;
    #pragma unroll
    for (int i = 0; i < 3; i++) {
        int c4 = lane + i * 64;                 // 156 float4 per row
        if (c4 < TFRAMES / 4) {
            float4 t = *(const float4*)(mp + c4 * 4);
            t.x = fmaxf(t.x, EPS); t.y = fmaxf(t.y, EPS);
            t.z = fmaxf(t.z, EPS); t.w = fmaxf(t.w, EPS);
            v[i] = t;
            sum += (t.x + t.y) + (t.z + t.w);
        } else {
            v[i] = make_float4(0.f, 0.f, 0.f, 0.f);
        }
    }
    #pragma unroll
    for (int off = 1; off < 64; off <<= 1) sum += __shfl_xor(sum, off, 64);
    const float mean = sum * (1.0f / (float)TFRAMES);

    float ssd = 0.f;
    #pragma unroll
    for (int i = 0; i < 3; i++) {
        int c4 = lane + i * 64;
        if (c4 < TFRAMES / 4) {
            float dx = v[i].x - mean, dy = v[i].y - mean;
            float dz = v[i].z - mean, dw = v[i].w - mean;
            ssd += (dx * dx + dy * dy) + (dz * dz + dw * dw);
        }
    }
    #pragma unroll
    for (int off = 1; off < 64; off <<= 1) ssd += __shfl_xor(ssd, off, 64);
    const float stdv = sqrtf(ssd * (1.0f / (float)(TFRAMES - 1)));
    const float inv = 1.0f / (stdv + EPS);

    float* fp = feat + (size_t)row * TFRAMES;
    #pragma unroll
    for (int i = 0; i < 3; i++) {
        int c4 = lane + i * 64;
        if (c4 < TFRAMES / 4) {
            float4 o;
            o.x = (v[i].x - mean) * inv; o.y = (v[i].y - mean) * inv;
            o.z = (v[i].z - mean) * inv; o.w = (v[i].w - mean) * inv;
            *(float4*)(fp + c4 * 4) = o;
        }
    }
}

// ---------------------------------------------------------------- launch ----
extern "C" void kernel_launch(void* const* d_in, const int* in_sizes, int n_in,
                              void* d_out, int out_size, void* d_ws, size_t ws_size,
                              hipStream_t stream) {
    const float* x = (const float*)d_in[0];
    unsigned short* Wc  = (unsigned short*)d_ws;            // 288*512 bf16
    unsigned short* Ws  = Wc + NFREQ_PAD * FRAME_LEN;       // 288*512 bf16
    unsigned short* xbf = Ws + NFREQ_PAD * FRAME_LEN;       // 64*160000 bf16
    float* mag  = (float*)d_out;                            // [64][257][624]
    float* feat = mag + (size_t)NBATCH * NFREQ * TFRAMES;

    prep<<<XBLKS + NFREQ_PAD, 256, 0, stream>>>(x, xbf, Wc, Ws);

    // 156 M-tiles x 9 F-tiles, linearized + XCD-swizzled in-kernel
    stft_mfma<<<156 * 9, 256, 0, stream>>>(xbf, Wc, Ws, mag);

    normalize<<<NBATCH * NFREQ / 4, 256, 0, stream>>>(mag, feat);
}